// Round 2
// baseline (440.406 us; speedup 1.0000x reference)
//
#include <hip/hip_runtime.h>

#define TH 32
#define TW 64
#define PW 88   // LDS row pitch in floats
#define IS2 0.70710678118654752f

__device__ __forceinline__ int symidx(int t, int n) {
    t = (t < 0) ? (-1 - t) : t;
    return (t >= n) ? (2 * n - 1 - t) : t;
}

// ================= border-path helpers (r1, proven) =================
__device__ __forceinline__ void col13_yl(
    float (&acc)[TH], const float* __restrict__ ylp,
    const float* __restrict__ taps, int r0, int cc)
{
    #pragma unroll
    for (int pi = 0; pi < TH + 12; ++pi) {
        int rr = symidx(r0 - 6 + pi, 256);
        float v = ylp[rr * 256 + cc];
        #pragma unroll
        for (int j = 0; j < 13; ++j) {
            int ro = pi + j - 12;
            if (ro >= 0 && ro < TH) acc[ro] = fmaf(taps[j], v, acc[ro]);
        }
    }
}

__device__ __forceinline__ void col13_c2q(
    float (&acc)[TH], const float* __restrict__ yhr, const float* __restrict__ yhi,
    int bA, int bB, const float* __restrict__ taps, int r0, int cc)
{
    const int cp = cc & 1;
    const int j2 = cc >> 1;
    #pragma unroll
    for (int pi = 0; pi < TH + 12; ++pi) {
        int rr = symidx(r0 - 6 + pi, 256);
        int rp = rr & 1;
        int i2 = rr >> 1;
        const float* base = (((rp ^ cp) != 0) ? yhi : yhr) + (i2 * 128 + j2);
        float A  = base[bA * 16384];
        float Bv = base[bB * 16384];
        float vA = (rp & cp)       ? -A  : A;
        float vB = (rp & (cp ^ 1)) ? -Bv : Bv;
        float v = (vA + vB) * IS2;
        #pragma unroll
        for (int j = 0; j < 13; ++j) {
            int ro = pi + j - 12;
            if (ro >= 0 && ro < TH) acc[ro] = fmaf(taps[j], v, acc[ro]);
        }
    }
}

__device__ __forceinline__ void col19_c2q(
    float (&acc)[TH], const float* __restrict__ yhr, const float* __restrict__ yhi,
    const float* __restrict__ taps, int r0, int cc)
{
    const int bA = 0, bB = 5;
    const int cp = cc & 1;
    const int j2 = cc >> 1;
    #pragma unroll
    for (int pi = 0; pi < TH + 18; ++pi) {
        int rr = symidx(r0 - 9 + pi, 256);
        int rp = rr & 1;
        int i2 = rr >> 1;
        const float* base = (((rp ^ cp) != 0) ? yhi : yhr) + (i2 * 128 + j2);
        float A  = base[bA * 16384];
        float Bv = base[bB * 16384];
        float vA = (rp & cp)       ? -A  : A;
        float vB = (rp & (cp ^ 1)) ? -Bv : Bv;
        float v = (vA + vB) * IS2;
        #pragma unroll
        for (int j = 0; j < 19; ++j) {
            int ro = pi + j - 18;
            if (ro >= 0 && ro < TH) acc[ro] = fmaf(taps[j], v, acc[ro]);
        }
    }
}

// ================= fast-path helpers (interior rows) =================
// Column-pair c2q column filter. Thread handles two adjacent staged columns
// sharing j2. accE accumulates the column whose SOURCE col is even-parity,
// accO the odd-parity one. Pair u loads (i2b+u); even row pi = EPI0+2u,
// odd row pi = EPI0+2u+1. All indices static after full unroll.
template<int L, int NP, int EPI0>
__device__ __forceinline__ void c2q_col_fast(
    float (&accE)[TH], float (&accO)[TH],
    const float* __restrict__ pRA, const float* __restrict__ pRB,
    const float* __restrict__ pIA, const float* __restrict__ pIB,
    int vof, const float* __restrict__ taps)
{
    #pragma unroll
    for (int u = 0; u < NP; ++u) {
        float Ar = pRA[vof + u * 128];
        float Br = pRB[vof + u * 128];
        float Ai = pIA[vof + u * 128];
        float Bi = pIB[vof + u * 128];
        float cee = (Ar + Br) * IS2;   // src-even col, even row
        float coe = (Ai + Bi) * IS2;   // src-odd  col, even row
        float ceo = (Ai - Bi) * IS2;   // src-even col, odd row
        float coo = (Br - Ar) * IS2;   // src-odd  col, odd row
        const int piE = EPI0 + 2 * u;
        #pragma unroll
        for (int j = 0; j < L; ++j) {
            int ro = piE + j - (L - 1);
            if (ro >= 0 && ro < TH) {
                accE[ro] = fmaf(taps[j], cee, accE[ro]);
                accO[ro] = fmaf(taps[j], coe, accO[ro]);
            }
        }
        #pragma unroll
        for (int j = 0; j < L; ++j) {
            int ro = piE + 1 + j - (L - 1);
            if (ro >= 0 && ro < TH) {
                accE[ro] = fmaf(taps[j], ceo, accE[ro]);
                accO[ro] = fmaf(taps[j], coo, accO[ro]);
            }
        }
    }
}

// Yl column-pair filter: float2 load per row, accX = column `lo`, accY = lo+1
__device__ __forceinline__ void yl_col_fast(
    float (&accX)[TH], float (&accY)[TH],
    const float* __restrict__ ylp, int rbase, int lo,
    const float* __restrict__ taps)
{
    #pragma unroll
    for (int pi = 0; pi < TH + 12; ++pi) {
        float2 v = *(const float2*)&ylp[(rbase + pi) * 256 + lo];
        #pragma unroll
        for (int j = 0; j < 13; ++j) {
            int ro = pi + j - 12;
            if (ro >= 0 && ro < TH) {
                accX[ro] = fmaf(taps[j], v.x, accX[ro]);
                accY[ro] = fmaf(taps[j], v.y, accY[ro]);
            }
        }
    }
}

extern "C" __global__ __launch_bounds__(512) void dtcwt_inv(
    const float* __restrict__ Yl, const float* __restrict__ Yhr,
    const float* __restrict__ Yhi,
    const float* __restrict__ g0, const float* __restrict__ g1,
    const float* __restrict__ g2, float* __restrict__ out)
{
    __shared__ __align__(16) float sT[4][TH][PW];

    const int tid = threadIdx.x;
    const int plane = blockIdx.z;
    const int r0 = blockIdx.y * TH;
    const int c0 = blockIdx.x * TW;

    const float* ylp = Yl  + (size_t)plane * 65536;
    const float* yhr = Yhr + (size_t)plane * 6 * 16384;
    const float* yhi = Yhi + (size_t)plane * 6 * 16384;

    const bool rowInterior = (blockIdx.y >= 1) && (blockIdx.y <= 6);

    if (rowInterior) {
        // ---------- fast stage 1: 4 active waves, column-pair threads ----------
        const int w = tid >> 6;
        const int p = tid & 63;
        if (w == 0) {
            if (p < 38) {                       // t1a = col_g0(Yl), ti in [6,82)
                int e0 = c0 - 6 + 2 * p;
                int s0 = symidx(e0, 256);
                int s1 = symidx(e0 + 1, 256);
                int lo = (s0 < s1) ? s0 : s1;   // lo is always even
                float accX[TH], accY[TH];
                #pragma unroll
                for (int i = 0; i < TH; ++i) { accX[i] = 0.f; accY[i] = 0.f; }
                yl_col_fast(accX, accY, ylp, r0 - 6, lo, g0);
                int ti0 = 6 + 2 * p;
                int sw = (s0 == lo) ? 0 : 1;    // swap at store if pair reflected
                #pragma unroll
                for (int ro = 0; ro < TH; ++ro) {
                    sT[0][ro][ti0 + sw]     = accX[ro];
                    sT[0][ro][ti0 + 1 - sw] = accY[ro];
                }
            }
        } else if (w == 1) {
            if (p < 38) {                       // t1b = col_g1(lh), bands 0,5
                int e0 = c0 - 6 + 2 * p;
                int s0 = symidx(e0, 256);
                int j2 = s0 >> 1;
                int q0 = s0 & 1;
                float accE[TH], accO[TH];
                #pragma unroll
                for (int i = 0; i < TH; ++i) { accE[i] = 0.f; accO[i] = 0.f; }
                int vof = ((r0 - 10) >> 1) * 128 + j2;
                c2q_col_fast<19, 26, -1>(accE, accO,
                    yhr + 0 * 16384, yhr + 5 * 16384,
                    yhi + 0 * 16384, yhi + 5 * 16384, vof, g1);
                int ti0 = 6 + 2 * p;
                #pragma unroll
                for (int ro = 0; ro < TH; ++ro) {
                    sT[1][ro][ti0 + q0]     = accE[ro];
                    sT[1][ro][ti0 + 1 - q0] = accO[ro];
                }
            }
        } else if (w == 2) {
            if (p < 42) {                       // t2 = col_g0(hl), bands 2,3, ti in [2,86)
                int e0 = c0 - 10 + 2 * p;
                int s0 = symidx(e0, 256);
                int j2 = s0 >> 1;
                int q0 = s0 & 1;
                float accE[TH], accO[TH];
                #pragma unroll
                for (int i = 0; i < TH; ++i) { accE[i] = 0.f; accO[i] = 0.f; }
                int vof = ((r0 - 6) >> 1) * 128 + j2;
                c2q_col_fast<13, 22, 0>(accE, accO,
                    yhr + 2 * 16384, yhr + 3 * 16384,
                    yhi + 2 * 16384, yhi + 3 * 16384, vof, g0);
                int ti0 = 2 + 2 * p;
                #pragma unroll
                for (int ro = 0; ro < TH; ++ro) {
                    sT[2][ro][ti0 + q0]     = accE[ro];
                    sT[2][ro][ti0 + 1 - q0] = accO[ro];
                }
            }
        } else if (w == 3) {
            if (p < 38) {                       // t3 = col_g2(hh), bands 1,4
                int e0 = c0 - 6 + 2 * p;
                int s0 = symidx(e0, 256);
                int j2 = s0 >> 1;
                int q0 = s0 & 1;
                float accE[TH], accO[TH];
                #pragma unroll
                for (int i = 0; i < TH; ++i) { accE[i] = 0.f; accO[i] = 0.f; }
                int vof = ((r0 - 6) >> 1) * 128 + j2;
                c2q_col_fast<13, 22, 0>(accE, accO,
                    yhr + 1 * 16384, yhr + 4 * 16384,
                    yhi + 1 * 16384, yhi + 4 * 16384, vof, g2);
                int ti0 = 6 + 2 * p;
                #pragma unroll
                for (int ro = 0; ro < TH; ++ro) {
                    sT[3][ro][ti0 + q0]     = accE[ro];
                    sT[3][ro][ti0 + 1 - q0] = accO[ro];
                }
            }
        }
    } else {
        // ---------- border stage 1 (r1 path, handles row reflection) ----------
        const int role = tid >> 7;
        const int lr   = tid & 127;
        float acc[TH];
        #pragma unroll
        for (int i = 0; i < TH; ++i) acc[i] = 0.0f;
        int ti = -1;
        if (role == 0) {
            if (lr < 76) {
                ti = lr + 6;
                int cc = symidx(c0 + ti - 12, 256);
                col13_yl(acc, ylp, g0, r0, cc);
            }
        } else if (role == 1) {
            if (lr < 76) {
                ti = lr + 6;
                int cc = symidx(c0 + ti - 12, 256);
                col19_c2q(acc, yhr, yhi, g1, r0, cc);
            }
        } else if (role == 2) {
            if (lr < 82) {
                ti = lr + 3;
                int cc = symidx(c0 + ti - 12, 256);
                col13_c2q(acc, yhr, yhi, 2, 3, g0, r0, cc);
            }
        } else {
            if (lr < 76) {
                ti = lr + 6;
                int cc = symidx(c0 + ti - 12, 256);
                col13_c2q(acc, yhr, yhi, 1, 4, g2, r0, cc);
            }
        }
        if (ti >= 0) {
            #pragma unroll
            for (int ro = 0; ro < TH; ++ro) sT[role][ro][ti] = acc[ro];
        }
    }
    __syncthreads();

    // ---------------- stage 2: row filters from LDS -> 4 outputs/thread ----------------
    const int cg = tid & 15;
    const int r  = tid >> 4;
    const int cb = 4 * cg;

    float w1[20];
    #pragma unroll
    for (int k = 0; k < 5; ++k) {
        float4 a = *(const float4*)&sT[0][r][cb + 4 + 4 * k];
        float4 b = *(const float4*)&sT[1][r][cb + 4 + 4 * k];
        w1[4*k+0] = a.x + b.x; w1[4*k+1] = a.y + b.y;
        w1[4*k+2] = a.z + b.z; w1[4*k+3] = a.w + b.w;
    }
    float w2[28];
    #pragma unroll
    for (int k = 0; k < 7; ++k) {
        float4 a = *(const float4*)&sT[2][r][cb + 4 * k];
        w2[4*k+0] = a.x; w2[4*k+1] = a.y; w2[4*k+2] = a.z; w2[4*k+3] = a.w;
    }
    float w3[20];
    #pragma unroll
    for (int k = 0; k < 5; ++k) {
        float4 a = *(const float4*)&sT[3][r][cb + 4 + 4 * k];
        w3[4*k+0] = a.x; w3[4*k+1] = a.y; w3[4*k+2] = a.z; w3[4*k+3] = a.w;
    }

    float4 res;
    float* rp = (float*)&res;
    #pragma unroll
    for (int q = 0; q < 4; ++q) {
        float s = 0.0f;
        #pragma unroll
        for (int j = 0; j < 13; ++j) s = fmaf(g0[j], w1[q + 14 - j], s);
        #pragma unroll
        for (int j = 0; j < 19; ++j) s = fmaf(g1[j], w2[q + 21 - j], s);
        #pragma unroll
        for (int j = 0; j < 13; ++j) s = fmaf(g2[j], w3[q + 14 - j], s);
        rp[q] = s;
    }
    *(float4*)&out[(size_t)plane * 65536 + (size_t)(r0 + r) * 256 + (c0 + cb)] = res;
}

extern "C" void kernel_launch(void* const* d_in, const int* in_sizes, int n_in,
                              void* d_out, int out_size, void* d_ws, size_t ws_size,
                              hipStream_t stream) {
    const float* Yl  = (const float*)d_in[0];
    const float* Yhr = (const float*)d_in[1];
    const float* Yhi = (const float*)d_in[2];
    const float* g0  = (const float*)d_in[3];
    const float* g1  = (const float*)d_in[4];
    const float* g2  = (const float*)d_in[5];
    float* out = (float*)d_out;

    dim3 grid(256 / TW, 256 / TH, 8 * 64);   // (4, 8, 512)
    dim3 block(512, 1, 1);
    dtcwt_inv<<<grid, block, 0, stream>>>(Yl, Yhr, Yhi, g0, g1, g2, out);
}

// Round 3
// 417.222 us; speedup vs baseline: 1.0556x; 1.0556x over previous
//
#include <hip/hip_runtime.h>

#define TH 32
#define TW 64
#define PW 88   // LDS row pitch in floats
#define IS2 0.70710678118654752f

__device__ __forceinline__ int symidx(int t, int n) {
    t = (t < 0) ? (-1 - t) : t;
    return (t >= n) ? (2 * n - 1 - t) : t;
}

// ================= border-path helpers (r1, proven) =================
__device__ __forceinline__ void col13_yl(
    float (&acc)[TH], const float* __restrict__ ylp,
    const float* __restrict__ taps, int r0, int cc)
{
    #pragma unroll
    for (int pi = 0; pi < TH + 12; ++pi) {
        int rr = symidx(r0 - 6 + pi, 256);
        float v = ylp[rr * 256 + cc];
        #pragma unroll
        for (int j = 0; j < 13; ++j) {
            int ro = pi + j - 12;
            if (ro >= 0 && ro < TH) acc[ro] = fmaf(taps[j], v, acc[ro]);
        }
    }
}

__device__ __forceinline__ void col13_c2q(
    float (&acc)[TH], const float* __restrict__ yhr, const float* __restrict__ yhi,
    int bA, int bB, const float* __restrict__ taps, int r0, int cc)
{
    const int cp = cc & 1;
    const int j2 = cc >> 1;
    #pragma unroll
    for (int pi = 0; pi < TH + 12; ++pi) {
        int rr = symidx(r0 - 6 + pi, 256);
        int rp = rr & 1;
        int i2 = rr >> 1;
        const float* base = (((rp ^ cp) != 0) ? yhi : yhr) + (i2 * 128 + j2);
        float A  = base[bA * 16384];
        float Bv = base[bB * 16384];
        float vA = (rp & cp)       ? -A  : A;
        float vB = (rp & (cp ^ 1)) ? -Bv : Bv;
        float v = (vA + vB) * IS2;
        #pragma unroll
        for (int j = 0; j < 13; ++j) {
            int ro = pi + j - 12;
            if (ro >= 0 && ro < TH) acc[ro] = fmaf(taps[j], v, acc[ro]);
        }
    }
}

__device__ __forceinline__ void col19_c2q(
    float (&acc)[TH], const float* __restrict__ yhr, const float* __restrict__ yhi,
    const float* __restrict__ taps, int r0, int cc)
{
    const int bA = 0, bB = 5;
    const int cp = cc & 1;
    const int j2 = cc >> 1;
    #pragma unroll
    for (int pi = 0; pi < TH + 18; ++pi) {
        int rr = symidx(r0 - 9 + pi, 256);
        int rp = rr & 1;
        int i2 = rr >> 1;
        const float* base = (((rp ^ cp) != 0) ? yhi : yhr) + (i2 * 128 + j2);
        float A  = base[bA * 16384];
        float Bv = base[bB * 16384];
        float vA = (rp & cp)       ? -A  : A;
        float vB = (rp & (cp ^ 1)) ? -Bv : Bv;
        float v = (vA + vB) * IS2;
        #pragma unroll
        for (int j = 0; j < 19; ++j) {
            int ro = pi + j - 18;
            if (ro >= 0 && ro < TH) acc[ro] = fmaf(taps[j], v, acc[ro]);
        }
    }
}

// ================= interior fast helper: single column, row-pair c2q =================
// Thread owns ONE staged column (parity cp hoisted). Pair u covers rows
// (even,odd) sharing i2; pE/pO are the arrays feeding even/odd rows, sgn
// folds the odd-row sign. All acc indices compile-time (guards pruned).
template<int L, int NP, int EPI0>
__device__ __forceinline__ void c2q_col_fast1(
    float (&acc)[TH],
    const float* __restrict__ pEA, const float* __restrict__ pEB,
    const float* __restrict__ pOA, const float* __restrict__ pOB,
    int vof, float sgn, const float* __restrict__ taps)
{
    #pragma unroll
    for (int u = 0; u < NP; ++u) {
        float Ae = pEA[vof + u * 128];
        float Be = pEB[vof + u * 128];
        float Ao = pOA[vof + u * 128];
        float Bo = pOB[vof + u * 128];
        float ve = (Ae + Be) * IS2;
        float vo = (Ao - Bo) * sgn;
        #pragma unroll
        for (int j = 0; j < L; ++j) {
            int ro = EPI0 + 2 * u + j - (L - 1);
            if (ro >= 0 && ro < TH) acc[ro] = fmaf(taps[j], ve, acc[ro]);
        }
        #pragma unroll
        for (int j = 0; j < L; ++j) {
            int ro = EPI0 + 2 * u + 1 + j - (L - 1);
            if (ro >= 0 && ro < TH) acc[ro] = fmaf(taps[j], vo, acc[ro]);
        }
    }
}

extern "C" __global__ __launch_bounds__(512) void dtcwt_inv(
    const float* __restrict__ Yl, const float* __restrict__ Yhr,
    const float* __restrict__ Yhi,
    const float* __restrict__ g0, const float* __restrict__ g1,
    const float* __restrict__ g2, float* __restrict__ out)
{
    __shared__ __align__(16) float sT[4][TH][PW];

    const int tid = threadIdx.x;
    const int plane = blockIdx.z;
    const int r0 = blockIdx.y * TH;
    const int c0 = blockIdx.x * TW;

    const float* ylp = Yl  + (size_t)plane * 65536;
    const float* yhr = Yhr + (size_t)plane * 6 * 16384;
    const float* yhi = Yhi + (size_t)plane * 6 * 16384;

    const bool rowInterior = (blockIdx.y >= 1) && (blockIdx.y <= 6);

    const int role = tid >> 7;
    const int lr   = tid & 127;

    float acc[TH];
    #pragma unroll
    for (int i = 0; i < TH; ++i) acc[i] = 0.0f;
    int ti = -1;

    if (rowInterior) {
        // ---------- fast stage 1: no symidx on rows, row-pair c2q ----------
        if (role == 0) {
            if (lr < 76) {
                ti = lr + 6;
                int cc = symidx(c0 + lr - 6, 256);
                const float* p = ylp + (r0 - 6) * 256 + cc;
                #pragma unroll
                for (int pi = 0; pi < TH + 12; ++pi) {
                    float v = p[pi * 256];
                    #pragma unroll
                    for (int j = 0; j < 13; ++j) {
                        int ro = pi + j - 12;
                        if (ro >= 0 && ro < TH) acc[ro] = fmaf(g0[j], v, acc[ro]);
                    }
                }
            }
        } else if (role == 1) {
            if (lr < 76) {                        // t1b = col_g1(lh), bands 0,5
                ti = lr + 6;
                int cc = symidx(c0 + lr - 6, 256);
                int cp = cc & 1, j2 = cc >> 1;
                const float* pE = cp ? yhi : yhr;
                const float* pO = cp ? yhr : yhi;
                float sgn = cp ? -IS2 : IS2;
                int vof = ((r0 - 10) >> 1) * 128 + j2;
                c2q_col_fast1<19, 26, -1>(acc,
                    pE + 0 * 16384, pE + 5 * 16384,
                    pO + 0 * 16384, pO + 5 * 16384, vof, sgn, g1);
            }
        } else if (role == 2) {
            if (lr < 82) {                        // t2 = col_g0(hl), bands 2,3
                ti = lr + 3;
                int cc = symidx(c0 + lr - 9, 256);
                int cp = cc & 1, j2 = cc >> 1;
                const float* pE = cp ? yhi : yhr;
                const float* pO = cp ? yhr : yhi;
                float sgn = cp ? -IS2 : IS2;
                int vof = ((r0 - 6) >> 1) * 128 + j2;
                c2q_col_fast1<13, 22, 0>(acc,
                    pE + 2 * 16384, pE + 3 * 16384,
                    pO + 2 * 16384, pO + 3 * 16384, vof, sgn, g0);
            }
        } else {
            if (lr < 76) {                        // t3 = col_g2(hh), bands 1,4
                ti = lr + 6;
                int cc = symidx(c0 + lr - 6, 256);
                int cp = cc & 1, j2 = cc >> 1;
                const float* pE = cp ? yhi : yhr;
                const float* pO = cp ? yhr : yhi;
                float sgn = cp ? -IS2 : IS2;
                int vof = ((r0 - 6) >> 1) * 128 + j2;
                c2q_col_fast1<13, 22, 0>(acc,
                    pE + 1 * 16384, pE + 4 * 16384,
                    pO + 1 * 16384, pO + 4 * 16384, vof, sgn, g2);
            }
        }
    } else {
        // ---------- border stage 1 (r1 path, handles row reflection) ----------
        if (role == 0) {
            if (lr < 76) {
                ti = lr + 6;
                int cc = symidx(c0 + ti - 12, 256);
                col13_yl(acc, ylp, g0, r0, cc);
            }
        } else if (role == 1) {
            if (lr < 76) {
                ti = lr + 6;
                int cc = symidx(c0 + ti - 12, 256);
                col19_c2q(acc, yhr, yhi, g1, r0, cc);
            }
        } else if (role == 2) {
            if (lr < 82) {
                ti = lr + 3;
                int cc = symidx(c0 + ti - 12, 256);
                col13_c2q(acc, yhr, yhi, 2, 3, g0, r0, cc);
            }
        } else {
            if (lr < 76) {
                ti = lr + 6;
                int cc = symidx(c0 + ti - 12, 256);
                col13_c2q(acc, yhr, yhi, 1, 4, g2, r0, cc);
            }
        }
    }
    if (ti >= 0) {
        #pragma unroll
        for (int ro = 0; ro < TH; ++ro) sT[role][ro][ti] = acc[ro];
    }
    __syncthreads();

    // ---------------- stage 2: row filters from LDS -> 4 outputs/thread ----------------
    const int cg = tid & 15;
    const int r  = tid >> 4;
    const int cb = 4 * cg;

    float w1[20];
    #pragma unroll
    for (int k = 0; k < 5; ++k) {
        float4 a = *(const float4*)&sT[0][r][cb + 4 + 4 * k];
        float4 b = *(const float4*)&sT[1][r][cb + 4 + 4 * k];
        w1[4*k+0] = a.x + b.x; w1[4*k+1] = a.y + b.y;
        w1[4*k+2] = a.z + b.z; w1[4*k+3] = a.w + b.w;
    }
    float w2[28];
    #pragma unroll
    for (int k = 0; k < 7; ++k) {
        float4 a = *(const float4*)&sT[2][r][cb + 4 * k];
        w2[4*k+0] = a.x; w2[4*k+1] = a.y; w2[4*k+2] = a.z; w2[4*k+3] = a.w;
    }
    float w3[20];
    #pragma unroll
    for (int k = 0; k < 5; ++k) {
        float4 a = *(const float4*)&sT[3][r][cb + 4 + 4 * k];
        w3[4*k+0] = a.x; w3[4*k+1] = a.y; w3[4*k+2] = a.z; w3[4*k+3] = a.w;
    }

    float4 res;
    float* rp = (float*)&res;
    #pragma unroll
    for (int q = 0; q < 4; ++q) {
        float s = 0.0f;
        #pragma unroll
        for (int j = 0; j < 13; ++j) s = fmaf(g0[j], w1[q + 14 - j], s);
        #pragma unroll
        for (int j = 0; j < 19; ++j) s = fmaf(g1[j], w2[q + 21 - j], s);
        #pragma unroll
        for (int j = 0; j < 13; ++j) s = fmaf(g2[j], w3[q + 14 - j], s);
        rp[q] = s;
    }
    *(float4*)&out[(size_t)plane * 65536 + (size_t)(r0 + r) * 256 + (c0 + cb)] = res;
}

extern "C" void kernel_launch(void* const* d_in, const int* in_sizes, int n_in,
                              void* d_out, int out_size, void* d_ws, size_t ws_size,
                              hipStream_t stream) {
    const float* Yl  = (const float*)d_in[0];
    const float* Yhr = (const float*)d_in[1];
    const float* Yhi = (const float*)d_in[2];
    const float* g0  = (const float*)d_in[3];
    const float* g1  = (const float*)d_in[4];
    const float* g2  = (const float*)d_in[5];
    float* out = (float*)d_out;

    dim3 grid(256 / TW, 256 / TH, 8 * 64);   // (4, 8, 512)
    dim3 block(512, 1, 1);
    dtcwt_inv<<<grid, block, 0, stream>>>(Yl, Yhr, Yhi, g0, g1, g2, out);
}